// Round 2
// baseline (5771.374 us; speedup 1.0000x reference)
//
#include <hip/hip_runtime.h>

typedef short short8 __attribute__((ext_vector_type(8)));
typedef float f32x4 __attribute__((ext_vector_type(4)));

#define T_STEPS 512
#define BATCH   128
#define EMBD    512
#define HID     1024
#define NWG     128
#define NTHR    1024

// ---- workspace layout (bytes) ----
#define BAR_OFF   0
#define H_OFF     256
#define H_ELEMS   131072                      // ushort per h buffer (128*1024)
#define WH_OFF    (H_OFF + 2*H_ELEMS*2)       // 524544
#define WH_ELEMS  (NWG*64*64*8)               // 4,194,304 ushort
#define WI_OFF    (WH_OFF + WH_ELEMS*2)
#define WI_ELEMS  (NWG*32*64*8)               // 2,097,152 ushort
#define BS_OFF    (WI_OFF + WI_ELEMS*2)
#define BS_ELEMS  (NWG*32)                    // float
#define PT_OFF    (BS_OFF + BS_ELEMS*4)
#define PT_ELEMS  (NWG*BATCH*2)               // float
#define EMB_OFF   (PT_OFF + PT_ELEMS*4)
#define EMB_ELEMS ((size_t)T_STEPS*16*8*64*8) // 33,554,432 ushort
#define WS_NEEDED (EMB_OFF + EMB_ELEMS*2)

__device__ __forceinline__ unsigned short f2b(float f) {
    unsigned u = __builtin_bit_cast(unsigned, f);
    u += 0x7FFFu + ((u >> 16) & 1u);
    return (unsigned short)(u >> 16);
}

__device__ __forceinline__ uint4 pack8(float4 a, float4 b) {
    uint4 r;
    r.x = (unsigned)f2b(a.x) | ((unsigned)f2b(a.y) << 16);
    r.y = (unsigned)f2b(a.z) | ((unsigned)f2b(a.w) << 16);
    r.z = (unsigned)f2b(b.x) | ((unsigned)f2b(b.y) << 16);
    r.w = (unsigned)f2b(b.z) | ((unsigned)f2b(b.w) << 16);
    return r;
}

__device__ __forceinline__ float fsig(float x) {
    float e = __expf(-fabsf(x));
    float r = 1.f / (1.f + e);
    return x >= 0.f ? r : 1.f - r;
}
__device__ __forceinline__ float ftanh_(float x) {
    float e = __expf(-2.f * fabsf(x));
    float r = (1.f - e) / (1.f + e);
    return x >= 0.f ? r : -r;
}

// W_hh [4096,1024] f32 -> bf16 fragment chunks: wh_arr[j][chunk=ks*2+nt][lane][8]
__global__ void prep_wh(const float* __restrict__ w_hh, unsigned short* __restrict__ wh_arr) {
    int gid = blockIdx.x * blockDim.x + threadIdx.x;   // < 128*64*64
    int l  = gid & 63;
    int c  = (gid >> 6) & 63;
    int j  = gid >> 12;
    int ks = c >> 1, nt = c & 1;
    int lr = nt * 16 + (l & 15);                       // local gate row 0..31
    int grow = (lr >> 3) * HID + j * 8 + (lr & 7);     // global gate row
    int k = ks * 32 + (l >> 4) * 8;
    const float4* src = reinterpret_cast<const float4*>(w_hh + (size_t)grow * HID + k);
    *reinterpret_cast<uint4*>(wh_arr + (size_t)gid * 8) = pack8(src[0], src[1]);
}

// W_ih [4096,512] f32 -> wi_arr[j][chunk=ks*2+nt][lane][8]
__global__ void prep_wi(const float* __restrict__ w_ih, unsigned short* __restrict__ wi_arr) {
    int gid = blockIdx.x * blockDim.x + threadIdx.x;   // < 128*32*64
    int l  = gid & 63;
    int c  = (gid >> 6) & 31;
    int j  = gid >> 11;
    int ks = c >> 1, nt = c & 1;
    int lr = nt * 16 + (l & 15);
    int grow = (lr >> 3) * HID + j * 8 + (lr & 7);
    int k = ks * 32 + (l >> 4) * 8;
    const float4* src = reinterpret_cast<const float4*>(w_ih + (size_t)grow * EMBD + k);
    *reinterpret_cast<uint4*>(wi_arr + (size_t)gid * 8) = pack8(src[0], src[1]);
}

__global__ void prep_bsum(const float* __restrict__ b_ih, const float* __restrict__ b_hh,
                          float* __restrict__ bs) {
    int gid = blockIdx.x * blockDim.x + threadIdx.x;   // < 128*32
    int lr = gid & 31, j = gid >> 5;
    int grow = (lr >> 3) * HID + j * 8 + (lr & 7);
    bs[gid] = b_ih[grow] + b_hh[grow];
}

// embedded bf16 fragment chunks: emb_arr[t][ks][mt][lane][8]
__global__ void prep_emb(const int* __restrict__ x, const float* __restrict__ emb,
                         unsigned short* __restrict__ emb_arr) {
    int gid = blockIdx.x * blockDim.x + threadIdx.x;   // < 512*16*8*64
    int l  = gid & 63;
    int mt = (gid >> 6) & 7;
    int ks = (gid >> 9) & 15;
    int t  = gid >> 13;
    int b  = mt * 16 + (l & 15);
    int k  = ks * 32 + (l >> 4) * 8;
    int tok = x[t * BATCH + b];
    const float4* src = reinterpret_cast<const float4*>(emb + (size_t)tok * EMBD + k);
    *reinterpret_cast<uint4*>(emb_arr + (size_t)gid * 8) = pack8(src[0], src[1]);
}

__global__ __launch_bounds__(NTHR, 1) void lstm_main(
    const unsigned short* __restrict__ wh_arr,
    const unsigned short* __restrict__ wi_arr,
    const float* __restrict__ bs_arr,
    const unsigned short* __restrict__ emb_arr,
    unsigned short* __restrict__ h_arr,
    const float* __restrict__ fc_w,
    float* __restrict__ partials,
    unsigned* __restrict__ bar)
{
    __shared__ __align__(16) unsigned short whs[64 * 64 * 8];   // 64 KB
    __shared__ __align__(16) unsigned short wis[32 * 64 * 8];   // 32 KB
    __shared__ __align__(16) float gbuf[2][BATCH * 33];         // 33 KB
    __shared__ float bss[32];

    const int tid = threadIdx.x;
    const int j   = blockIdx.x;

    {   // one-time LDS fill of this WG's weight slices
        const uint4* s = reinterpret_cast<const uint4*>(wh_arr + (size_t)j * 32768);
        uint4* d = reinterpret_cast<uint4*>(whs);
        for (int i = tid; i < 4096; i += NTHR) d[i] = s[i];
        const uint4* s2 = reinterpret_cast<const uint4*>(wi_arr + (size_t)j * 16384);
        uint4* d2 = reinterpret_cast<uint4*>(wis);
        for (int i = tid; i < 2048; i += NTHR) d2[i] = s2[i];
        if (tid < 32) bss[tid] = bs_arr[j * 32 + tid];
    }
    __syncthreads();

    const int lane = tid & 63;
    const int wave = tid >> 6;     // 0..15
    const int mt   = wave >> 1;    // m-tile 0..7 (16 batch rows each)
    const int kh   = wave & 1;     // k-half

    // pointwise ownership: one (batch, hcol) pair per thread
    const int pb   = tid >> 3;         // 0..127
    const int phc  = tid & 7;          // 0..7
    const int pcol = j * 8 + phc;      // global h column
    const int hks   = pcol >> 5;
    const int hlane = (((pcol & 31) >> 3) << 4) | (pb & 15);
    const int hmt   = pb >> 4;
    const int hidx  = ((hks * 8 + hmt) * 64 + hlane) * 8 + (pcol & 7);

    float c = 0.f, lasth = 0.f;
    unsigned target = NWG;

    for (int t = 0; t < T_STEPS; ++t) {
        f32x4 acc0 = {0.f, 0.f, 0.f, 0.f};
        f32x4 acc1 = {0.f, 0.f, 0.f, 0.f};
        const unsigned short* hbuf = h_arr + (t & 1) * H_ELEMS;
        const int ksb = kh * 16;
        #pragma unroll 4
        for (int ks = ksb; ks < ksb + 16; ++ks) {
            short8 a  = *reinterpret_cast<const short8*>(hbuf + ((ks * 8 + mt) * 64 + lane) * 8);
            short8 b0 = *reinterpret_cast<const short8*>(whs + ((ks * 2 + 0) * 64 + lane) * 8);
            short8 b1 = *reinterpret_cast<const short8*>(whs + ((ks * 2 + 1) * 64 + lane) * 8);
            acc0 = __builtin_amdgcn_mfma_f32_16x16x32_bf16(a, b0, acc0, 0, 0, 0);
            acc1 = __builtin_amdgcn_mfma_f32_16x16x32_bf16(a, b1, acc1, 0, 0, 0);
        }
        const unsigned short* ebuf = emb_arr + (size_t)t * 65536;
        const int keb = kh * 8;
        #pragma unroll 4
        for (int ks = keb; ks < keb + 8; ++ks) {
            short8 a  = *reinterpret_cast<const short8*>(ebuf + ((ks * 8 + mt) * 64 + lane) * 8);
            short8 b0 = *reinterpret_cast<const short8*>(wis + ((ks * 2 + 0) * 64 + lane) * 8);
            short8 b1 = *reinterpret_cast<const short8*>(wis + ((ks * 2 + 1) * 64 + lane) * 8);
            acc0 = __builtin_amdgcn_mfma_f32_16x16x32_bf16(a, b0, acc0, 0, 0, 0);
            acc1 = __builtin_amdgcn_mfma_f32_16x16x32_bf16(a, b1, acc1, 0, 0, 0);
        }
        {   // D frag -> gbuf[kh]  (row m = (lane>>4)*4+jj, col n = lane&15)
            int bl = mt * 16 + ((lane >> 4) << 2);
            float* g = &gbuf[kh][0];
            #pragma unroll
            for (int jj = 0; jj < 4; ++jj) {
                g[(bl + jj) * 33 + (lane & 15)]      = acc0[jj];
                g[(bl + jj) * 33 + 16 + (lane & 15)] = acc1[jj];
            }
        }
        __syncthreads();
        {   // LSTM pointwise: i,f,g,o at lr = {hc, 8+hc, 16+hc, 24+hc}
            float xi = gbuf[0][pb * 33 + phc]      + gbuf[1][pb * 33 + phc]      + bss[phc];
            float xf = gbuf[0][pb * 33 + 8 + phc]  + gbuf[1][pb * 33 + 8 + phc]  + bss[8 + phc];
            float xg = gbuf[0][pb * 33 + 16 + phc] + gbuf[1][pb * 33 + 16 + phc] + bss[16 + phc];
            float xo = gbuf[0][pb * 33 + 24 + phc] + gbuf[1][pb * 33 + 24 + phc] + bss[24 + phc];
            float ig = fsig(xi), fg = fsig(xf), gg = ftanh_(xg), og = fsig(xo);
            c = fg * c + ig * gg;
            float h = og * ftanh_(c);
            lasth = h;
            h_arr[((t + 1) & 1) * H_ELEMS + hidx] = f2b(h);
        }
        __syncthreads();   // gbuf consumed; h stores drained at the release-add
        if (tid == 0) {
            __hip_atomic_fetch_add(bar, 1u, __ATOMIC_RELEASE, __HIP_MEMORY_SCOPE_AGENT);
            // acquire-ordered spin: the load that observes the final release-add
            // synchronizes-with every WG's h stores for this step
            while (__hip_atomic_load(bar, __ATOMIC_ACQUIRE, __HIP_MEMORY_SCOPE_AGENT) < target) {}
        }
        target += NWG;
        __syncthreads();
    }

    {   // deterministic per-WG partial of out = h_T @ fc_w^T  (reduce over 8 lanes = 8 hcols)
        float v0 = lasth * fc_w[0 * HID + pcol];
        float v1 = lasth * fc_w[1 * HID + pcol];
        #pragma unroll
        for (int m = 1; m < 8; m <<= 1) {
            v0 += __shfl_xor(v0, m);
            v1 += __shfl_xor(v1, m);
        }
        if (phc == 0) {
            partials[(j * BATCH + pb) * 2 + 0] = v0;
            partials[(j * BATCH + pb) * 2 + 1] = v1;
        }
    }
}

__global__ void finalize(const float* __restrict__ partials, const float* __restrict__ fc_b,
                         float* __restrict__ out) {
    int tid = threadIdx.x;             // 256
    int b = tid >> 1, o = tid & 1;
    float s = fc_b[o];
    for (int j = 0; j < NWG; ++j) s += partials[(j * BATCH + b) * 2 + o];
    out[b * 2 + o] = s;
}

extern "C" void kernel_launch(void* const* d_in, const int* in_sizes, int n_in,
                              void* d_out, int out_size, void* d_ws, size_t ws_size,
                              hipStream_t stream) {
    const int*   x    = (const int*)d_in[0];
    const float* emb  = (const float*)d_in[1];
    const float* w_ih = (const float*)d_in[2];
    const float* w_hh = (const float*)d_in[3];
    const float* b_ih = (const float*)d_in[4];
    const float* b_hh = (const float*)d_in[5];
    const float* fc_w = (const float*)d_in[6];
    const float* fc_b = (const float*)d_in[7];
    float* out = (float*)d_out;
    char* ws = (char*)d_ws;

    if (ws_size < WS_NEEDED) {
        // distinctive failure marker: NaN fill tells us the workspace is too small
        (void)hipMemsetAsync(d_out, 0xFF, (size_t)out_size * sizeof(float), stream);
        return;
    }

    unsigned*       bar     = (unsigned*)(ws + BAR_OFF);
    unsigned short* h_arr   = (unsigned short*)(ws + H_OFF);
    unsigned short* wh_arr  = (unsigned short*)(ws + WH_OFF);
    unsigned short* wi_arr  = (unsigned short*)(ws + WI_OFF);
    float*          bs_arr  = (float*)(ws + BS_OFF);
    float*          pt_arr  = (float*)(ws + PT_OFF);
    unsigned short* emb_arr = (unsigned short*)(ws + EMB_OFF);

    // zero barrier counter + both h buffers (contiguous region at ws start)
    (void)hipMemsetAsync(ws, 0, 256 + (size_t)2 * H_ELEMS * 2, stream);

    prep_wh  <<<2048, 256, 0, stream>>>(w_hh, wh_arr);
    prep_wi  <<<1024, 256, 0, stream>>>(w_ih, wi_arr);
    prep_bsum<<<16,   256, 0, stream>>>(b_ih, b_hh, bs_arr);
    prep_emb <<<16384,256, 0, stream>>>(x, emb, emb_arr);
    lstm_main<<<NWG, NTHR, 0, stream>>>(wh_arr, wi_arr, bs_arr, emb_arr, h_arr,
                                        fc_w, pt_arr, bar);
    finalize <<<1, 256, 0, stream>>>(pt_arr, fc_b, out);
}

// Round 3
// 5194.635 us; speedup vs baseline: 1.1110x; 1.1110x over previous
//
#include <hip/hip_runtime.h>

typedef short short8 __attribute__((ext_vector_type(8)));
typedef float f32x4 __attribute__((ext_vector_type(4)));

#define T_STEPS 512
#define BATCH   128
#define EMBD    512
#define HID     1024
#define NWG     128
#define NTHR    1024

// ---- workspace layout (bytes) ----
#define SLOT_OFF    0
#define SLOT_STRIDE 16                        // uints per slot (64 B padding)
#define SLOT_BYTES  (NWG * SLOT_STRIDE * 4)   // 8192
#define H_OFF     SLOT_BYTES
#define H_ELEMS   131072                      // ushort per h buffer (128*1024)
#define WH_OFF    (H_OFF + 2*H_ELEMS*2)
#define WH_ELEMS  (NWG*64*64*8)               // 4,194,304 ushort
#define WI_OFF    (WH_OFF + WH_ELEMS*2)
#define WI_ELEMS  (NWG*32*64*8)               // 2,097,152 ushort
#define BS_OFF    (WI_OFF + WI_ELEMS*2)
#define BS_ELEMS  (NWG*32)                    // float
#define PT_OFF    (BS_OFF + BS_ELEMS*4)
#define PT_ELEMS  (NWG*BATCH*2)               // float
#define EMB_OFF   (PT_OFF + PT_ELEMS*4)
#define EMB_ELEMS ((size_t)T_STEPS*16*8*64*8) // 33,554,432 ushort
#define WS_NEEDED (EMB_OFF + EMB_ELEMS*2)

__device__ __forceinline__ unsigned short f2b(float f) {
    unsigned u = __builtin_bit_cast(unsigned, f);
    u += 0x7FFFu + ((u >> 16) & 1u);
    return (unsigned short)(u >> 16);
}

__device__ __forceinline__ uint4 pack8(float4 a, float4 b) {
    uint4 r;
    r.x = (unsigned)f2b(a.x) | ((unsigned)f2b(a.y) << 16);
    r.y = (unsigned)f2b(a.z) | ((unsigned)f2b(a.w) << 16);
    r.z = (unsigned)f2b(b.x) | ((unsigned)f2b(b.y) << 16);
    r.w = (unsigned)f2b(b.z) | ((unsigned)f2b(b.w) << 16);
    return r;
}

__device__ __forceinline__ float fsig(float x) {
    float e = __expf(-fabsf(x));
    float r = 1.f / (1.f + e);
    return x >= 0.f ? r : 1.f - r;
}
__device__ __forceinline__ float ftanh_(float x) {
    float e = __expf(-2.f * fabsf(x));
    float r = (1.f - e) / (1.f + e);
    return x >= 0.f ? r : -r;
}

// W_hh [4096,1024] f32 -> bf16 fragment chunks: wh_arr[j][chunk=ks*2+nt][lane][8]
__global__ void prep_wh(const float* __restrict__ w_hh, unsigned short* __restrict__ wh_arr) {
    int gid = blockIdx.x * blockDim.x + threadIdx.x;   // < 128*64*64
    int l  = gid & 63;
    int c  = (gid >> 6) & 63;
    int j  = gid >> 12;
    int ks = c >> 1, nt = c & 1;
    int lr = nt * 16 + (l & 15);                       // local gate row 0..31
    int grow = (lr >> 3) * HID + j * 8 + (lr & 7);     // global gate row
    int k = ks * 32 + (l >> 4) * 8;
    const float4* src = reinterpret_cast<const float4*>(w_hh + (size_t)grow * HID + k);
    *reinterpret_cast<uint4*>(wh_arr + (size_t)gid * 8) = pack8(src[0], src[1]);
}

// W_ih [4096,512] f32 -> wi_arr[j][chunk=ks*2+nt][lane][8]
__global__ void prep_wi(const float* __restrict__ w_ih, unsigned short* __restrict__ wi_arr) {
    int gid = blockIdx.x * blockDim.x + threadIdx.x;   // < 128*32*64
    int l  = gid & 63;
    int c  = (gid >> 6) & 31;
    int j  = gid >> 11;
    int ks = c >> 1, nt = c & 1;
    int lr = nt * 16 + (l & 15);
    int grow = (lr >> 3) * HID + j * 8 + (lr & 7);
    int k = ks * 32 + (l >> 4) * 8;
    const float4* src = reinterpret_cast<const float4*>(w_ih + (size_t)grow * EMBD + k);
    *reinterpret_cast<uint4*>(wi_arr + (size_t)gid * 8) = pack8(src[0], src[1]);
}

__global__ void prep_bsum(const float* __restrict__ b_ih, const float* __restrict__ b_hh,
                          float* __restrict__ bs) {
    int gid = blockIdx.x * blockDim.x + threadIdx.x;   // < 128*32
    int lr = gid & 31, j = gid >> 5;
    int grow = (lr >> 3) * HID + j * 8 + (lr & 7);
    bs[gid] = b_ih[grow] + b_hh[grow];
}

// embedded bf16 fragment chunks: emb_arr[t][ks][mt][lane][8]
__global__ void prep_emb(const int* __restrict__ x, const float* __restrict__ emb,
                         unsigned short* __restrict__ emb_arr) {
    int gid = blockIdx.x * blockDim.x + threadIdx.x;   // < 512*16*8*64
    int l  = gid & 63;
    int mt = (gid >> 6) & 7;
    int ks = (gid >> 9) & 15;
    int t  = gid >> 13;
    int b  = mt * 16 + (l & 15);
    int k  = ks * 32 + (l >> 4) * 8;
    int tok = x[t * BATCH + b];
    const float4* src = reinterpret_cast<const float4*>(emb + (size_t)tok * EMBD + k);
    *reinterpret_cast<uint4*>(emb_arr + (size_t)gid * 8) = pack8(src[0], src[1]);
}

__global__ __launch_bounds__(NTHR, 1) void lstm_main(
    const unsigned short* __restrict__ wh_arr,
    const unsigned short* __restrict__ wi_arr,
    const float* __restrict__ bs_arr,
    const unsigned short* __restrict__ emb_arr,
    unsigned short* __restrict__ h_arr,
    const float* __restrict__ fc_w,
    float* __restrict__ partials,
    unsigned* __restrict__ slots)
{
    __shared__ __align__(16) unsigned short whs[64 * 64 * 8];   // 64 KB
    __shared__ __align__(16) unsigned short wis[32 * 64 * 8];   // 32 KB
    __shared__ __align__(16) float gbuf[2][BATCH * 36];         // 36 KB, stride 36: <=2 lanes/bank
    __shared__ float bss[32];

    const int tid = threadIdx.x;
    const int j   = blockIdx.x;

    {   // one-time LDS fill of this WG's weight slices
        const uint4* s = reinterpret_cast<const uint4*>(wh_arr + (size_t)j * 32768);
        uint4* d = reinterpret_cast<uint4*>(whs);
        for (int i = tid; i < 4096; i += NTHR) d[i] = s[i];
        const uint4* s2 = reinterpret_cast<const uint4*>(wi_arr + (size_t)j * 16384);
        uint4* d2 = reinterpret_cast<uint4*>(wis);
        for (int i = tid; i < 2048; i += NTHR) d2[i] = s2[i];
        if (tid < 32) bss[tid] = bs_arr[j * 32 + tid];
    }
    __syncthreads();

    const int lane = tid & 63;
    const int wave = tid >> 6;     // 0..15
    const int mt   = wave >> 1;    // m-tile 0..7 (16 batch rows each)
    const int kh   = wave & 1;     // k-half

    // pointwise ownership: one (batch, hcol) pair per thread
    const int pb   = tid >> 3;         // 0..127
    const int phc  = tid & 7;          // 0..7
    const int pcol = j * 8 + phc;      // global h column
    const int hks   = pcol >> 5;
    const int hlane = (((pcol & 31) >> 3) << 4) | (pb & 15);
    const int hmt   = pb >> 4;
    const int hidx  = ((hks * 8 + hmt) * 64 + hlane) * 8 + (pcol & 7);

    float c = 0.f, lasth = 0.f;

    for (int t = 0; t < T_STEPS; ++t) {
        f32x4 acc0 = {0.f, 0.f, 0.f, 0.f};
        f32x4 acc1 = {0.f, 0.f, 0.f, 0.f};

        // ---- emb part first: independent of h / barrier, overlaps arrival skew ----
        const unsigned short* ebuf = emb_arr + (size_t)t * 65536;
        const int keb = kh * 8;
        #pragma unroll
        for (int ks = keb; ks < keb + 8; ++ks) {
            short8 a  = *reinterpret_cast<const short8*>(ebuf + ((ks * 8 + mt) * 64 + lane) * 8);
            short8 b0 = *reinterpret_cast<const short8*>(wis + ((ks * 2 + 0) * 64 + lane) * 8);
            short8 b1 = *reinterpret_cast<const short8*>(wis + ((ks * 2 + 1) * 64 + lane) * 8);
            acc0 = __builtin_amdgcn_mfma_f32_16x16x32_bf16(a, b0, acc0, 0, 0, 0);
            acc1 = __builtin_amdgcn_mfma_f32_16x16x32_bf16(a, b1, acc1, 0, 0, 0);
        }

        // ---- wait for h_t (all WGs arrived with value >= t); t=0: h=0, skip ----
        if (t > 0) {
            if (tid < NWG) {
                // relaxed agent-scope polls (sc1: served past L2, no per-poll inv)
                while (__hip_atomic_load(&slots[tid * SLOT_STRIDE],
                                         __ATOMIC_RELAXED, __HIP_MEMORY_SCOPE_AGENT) < (unsigned)t) {}
            }
            __syncthreads();
            if (tid == 0) {
                // single acquire: one buffer_inv so this CU refetches h from coherence point
                (void)__hip_atomic_load(&slots[0], __ATOMIC_ACQUIRE, __HIP_MEMORY_SCOPE_AGENT);
            }
            __syncthreads();

            const unsigned short* hbuf = h_arr + (t & 1) * H_ELEMS;
            const int ksb = kh * 16;
            #pragma unroll 8
            for (int ks = ksb; ks < ksb + 16; ++ks) {
                short8 a  = *reinterpret_cast<const short8*>(hbuf + ((ks * 8 + mt) * 64 + lane) * 8);
                short8 b0 = *reinterpret_cast<const short8*>(whs + ((ks * 2 + 0) * 64 + lane) * 8);
                short8 b1 = *reinterpret_cast<const short8*>(whs + ((ks * 2 + 1) * 64 + lane) * 8);
                acc0 = __builtin_amdgcn_mfma_f32_16x16x32_bf16(a, b0, acc0, 0, 0, 0);
                acc1 = __builtin_amdgcn_mfma_f32_16x16x32_bf16(a, b1, acc1, 0, 0, 0);
            }
        }

        {   // D frag -> gbuf[kh]  (row m = (lane>>4)*4+jj, col n = lane&15)
            int bl = mt * 16 + ((lane >> 4) << 2);
            float* g = &gbuf[kh][0];
            #pragma unroll
            for (int jj = 0; jj < 4; ++jj) {
                g[(bl + jj) * 36 + (lane & 15)]      = acc0[jj];
                g[(bl + jj) * 36 + 16 + (lane & 15)] = acc1[jj];
            }
        }
        __syncthreads();
        {   // LSTM pointwise: i,f,g,o at lr = {hc, 8+hc, 16+hc, 24+hc}
            float xi = gbuf[0][pb * 36 + phc]      + gbuf[1][pb * 36 + phc]      + bss[phc];
            float xf = gbuf[0][pb * 36 + 8 + phc]  + gbuf[1][pb * 36 + 8 + phc]  + bss[8 + phc];
            float xg = gbuf[0][pb * 36 + 16 + phc] + gbuf[1][pb * 36 + 16 + phc] + bss[16 + phc];
            float xo = gbuf[0][pb * 36 + 24 + phc] + gbuf[1][pb * 36 + 24 + phc] + bss[24 + phc];
            float ig = fsig(xi), fg = fsig(xf), gg = ftanh_(xg), og = fsig(xo);
            c = fg * c + ig * gg;
            float h = og * ftanh_(c);
            lasth = h;
            h_arr[((t + 1) & 1) * H_ELEMS + hidx] = f2b(h);
        }
        __syncthreads();   // h stores issued by all threads before the release below
        if (tid == 0) {
            // arrival: own padded slot, no RMW contention; release emits wbl2 so our
            // h lines reach the coherence point before the slot value is visible
            __hip_atomic_store(&slots[j * SLOT_STRIDE], (unsigned)(t + 1),
                               __ATOMIC_RELEASE, __HIP_MEMORY_SCOPE_AGENT);
        }
    }

    {   // deterministic per-WG partial of out = h_T @ fc_w^T  (reduce over 8 lanes = 8 hcols)
        float v0 = lasth * fc_w[0 * HID + pcol];
        float v1 = lasth * fc_w[1 * HID + pcol];
        #pragma unroll
        for (int m = 1; m < 8; m <<= 1) {
            v0 += __shfl_xor(v0, m);
            v1 += __shfl_xor(v1, m);
        }
        if (phc == 0) {
            partials[(j * BATCH + pb) * 2 + 0] = v0;
            partials[(j * BATCH + pb) * 2 + 1] = v1;
        }
    }
}

__global__ void finalize(const float* __restrict__ partials, const float* __restrict__ fc_b,
                         float* __restrict__ out) {
    int tid = threadIdx.x;             // 256
    int b = tid >> 1, o = tid & 1;
    float s = fc_b[o];
    for (int j = 0; j < NWG; ++j) s += partials[(j * BATCH + b) * 2 + o];
    out[b * 2 + o] = s;
}

extern "C" void kernel_launch(void* const* d_in, const int* in_sizes, int n_in,
                              void* d_out, int out_size, void* d_ws, size_t ws_size,
                              hipStream_t stream) {
    const int*   x    = (const int*)d_in[0];
    const float* emb  = (const float*)d_in[1];
    const float* w_ih = (const float*)d_in[2];
    const float* w_hh = (const float*)d_in[3];
    const float* b_ih = (const float*)d_in[4];
    const float* b_hh = (const float*)d_in[5];
    const float* fc_w = (const float*)d_in[6];
    const float* fc_b = (const float*)d_in[7];
    float* out = (float*)d_out;
    char* ws = (char*)d_ws;

    if (ws_size < WS_NEEDED) {
        // distinctive failure marker: NaN fill tells us the workspace is too small
        (void)hipMemsetAsync(d_out, 0xFF, (size_t)out_size * sizeof(float), stream);
        return;
    }

    unsigned*       slots   = (unsigned*)(ws + SLOT_OFF);
    unsigned short* h_arr   = (unsigned short*)(ws + H_OFF);
    unsigned short* wh_arr  = (unsigned short*)(ws + WH_OFF);
    unsigned short* wi_arr  = (unsigned short*)(ws + WI_OFF);
    float*          bs_arr  = (float*)(ws + BS_OFF);
    float*          pt_arr  = (float*)(ws + PT_OFF);
    unsigned short* emb_arr = (unsigned short*)(ws + EMB_OFF);

    // zero the arrival slots (h buffers need no init: t=0 skips the h-MFMA)
    (void)hipMemsetAsync(ws, 0, SLOT_BYTES, stream);

    prep_wh  <<<2048, 256, 0, stream>>>(w_hh, wh_arr);
    prep_wi  <<<1024, 256, 0, stream>>>(w_ih, wi_arr);
    prep_bsum<<<16,   256, 0, stream>>>(b_ih, b_hh, bs_arr);
    prep_emb <<<16384,256, 0, stream>>>(x, emb, emb_arr);
    lstm_main<<<NWG, NTHR, 0, stream>>>(wh_arr, wi_arr, bs_arr, emb_arr, h_arr,
                                        fc_w, pt_arr, slots);
    finalize <<<1, 256, 0, stream>>>(pt_arr, fc_b, out);
}